// Round 5
// baseline (872.477 us; speedup 1.0000x reference)
//
#include <hip/hip_runtime.h>

// TargetModel_78786880077968: 2-layer GCN + mean pool (all f32)
#define NN 100000      // nodes
#define NE 1600000     // edges
#define NG 512         // graphs
#define FD 64          // feature dim
#define NSL 8          // feature slices (XCD-pinned); 8 floats each = 32 B rows
#define SLF 8          // floats per slice
#define CHUNK 128      // nodes per agg block
#define SCAN_CHUNK 1024
#define SCAN_BLOCKS 98  // ceil(NN / SCAN_CHUNK)

// ---------- CSR build ----------

__global__ void k_count_rank(const int* __restrict__ dst, int* __restrict__ cnt,
                             int* __restrict__ rank, int e) {
    int i = blockIdx.x * 256 + threadIdx.x;
    if (i < e) rank[i] = atomicAdd(&cnt[dst[i]], 1);
}

__global__ void k_scan1(const int* __restrict__ cnt, int* __restrict__ part,
                        int* __restrict__ blockSum, int n) {
    __shared__ int lds[256];
    int tid = threadIdx.x;
    int base = blockIdx.x * SCAN_CHUNK + tid * 4;
    int v0 = (base + 0 < n) ? cnt[base + 0] : 0;
    int v1 = (base + 1 < n) ? cnt[base + 1] : 0;
    int v2 = (base + 2 < n) ? cnt[base + 2] : 0;
    int v3 = (base + 3 < n) ? cnt[base + 3] : 0;
    int s = v0 + v1 + v2 + v3;
    lds[tid] = s;
    __syncthreads();
    for (int off = 1; off < 256; off <<= 1) {
        int t = (tid >= off) ? lds[tid - off] : 0;
        __syncthreads();
        lds[tid] += t;
        __syncthreads();
    }
    int run = lds[tid] - s;
    if (base + 0 < n) part[base + 0] = run; run += v0;
    if (base + 1 < n) part[base + 1] = run; run += v1;
    if (base + 2 < n) part[base + 2] = run; run += v2;
    if (base + 3 < n) part[base + 3] = run;
    if (tid == 255) blockSum[blockIdx.x] = lds[255];
}

__global__ void k_scan2(const int* __restrict__ bs, int* __restrict__ boff, int nb) {
    __shared__ int lds[128];
    int tid = threadIdx.x;
    int v = (tid < nb) ? bs[tid] : 0;
    lds[tid] = v;
    __syncthreads();
    for (int off = 1; off < 128; off <<= 1) {
        int t = (tid >= off) ? lds[tid - off] : 0;
        __syncthreads();
        lds[tid] += t;
        __syncthreads();
    }
    if (tid < nb) boff[tid] = lds[tid] - v;
}

__global__ void k_scan3(int* __restrict__ rowptr, const int* __restrict__ boff,
                        const int* __restrict__ cnt, float* __restrict__ dinv,
                        const int* __restrict__ batch, int* __restrict__ pcnt, int n) {
    int i = blockIdx.x * 256 + threadIdx.x;
    if (i < n) {
        rowptr[i] = rowptr[i] + boff[i >> 10];
        float deg = (float)(cnt[i] + 1);  // +1 self loop
        dinv[i] = 1.0f / sqrtf(deg);
        atomicAdd(&pcnt[batch[i]], 1);
    }
}

__global__ void k_fill(const int* __restrict__ src, const int* __restrict__ dst,
                       const int* __restrict__ rank, const int* __restrict__ rowptr,
                       int* __restrict__ colidx, int e) {
    int i = blockIdx.x * 256 + threadIdx.x;
    if (i < e) {
        int d = dst[i];
        colidx[rowptr[d] + rank[i]] = src[i];
    }
}

// ---------- dense GEMM, sliced output ----------
// outs[s][row][f8] = dinv[row] * sum_k in[row][k] * W[k][s*8+f8]
// 4 waves/block, 4 rows/wave; lane c in 0..15 computes feats 4c..4c+3.
__global__ void k_gemm_scale(const float* __restrict__ in, const float* __restrict__ W,
                             const float* __restrict__ dinv, float* __restrict__ outs, int n) {
    __shared__ float w[FD * FD];        // 16 KB
    __shared__ float xr[4][4][80];      // padded f32 row staging
    int tid = threadIdx.x;
    {
        const float4* W4 = (const float4*)W;
        float4* w4s = (float4*)w;
        for (int i = tid; i < FD * FD / 4; i += 256) w4s[i] = W4[i];
    }
    int wave = tid >> 6, lane = tid & 63;
    int r = lane >> 4;        // row within wave
    int c = lane & 15;        // 4-feature chunk
    int row = blockIdx.x * 16 + wave * 4 + r;
    bool valid = row < n;
    if (valid) {
        float4 xv = ((const float4*)in)[row * 16 + c];
        *((float4*)&xr[wave][r][c * 4]) = xv;
    }
    __syncthreads();
    if (!valid) return;
    const float4* w4 = (const float4*)w;
    float4 acc = {0.f, 0.f, 0.f, 0.f};
#pragma unroll
    for (int k = 0; k < FD; ++k) {
        float xv = xr[wave][r][k];
        float4 wv = w4[k * 16 + c];
        acc.x = fmaf(xv, wv.x, acc.x);
        acc.y = fmaf(xv, wv.y, acc.y);
        acc.z = fmaf(xv, wv.z, acc.z);
        acc.w = fmaf(xv, wv.w, acc.w);
    }
    float d = dinv[row];
    acc.x *= d; acc.y *= d; acc.z *= d; acc.w *= d;
    int s = c >> 1, half = c & 1;     // slice, 16B-half within 32B slice row
    float4* dst = (float4*)(outs + ((size_t)s * NN + row) * SLF + half * 4);
    *dst = acc;
}

// ---------- sliced aggregation: block pinned to slice = bid&7 (XCD-local L2) ----
// lane = (slot 0..7, f 0..7). Per node: acc_f = sum over neighbors of S[nb][f].
template <int POOL>
__global__ void k_agg_sliced(const float* __restrict__ hs, const int* __restrict__ rowptr,
                             const int* __restrict__ cnt, const int* __restrict__ colidx,
                             const float* __restrict__ dinv, const float* __restrict__ b,
                             const int* __restrict__ batch, float* __restrict__ outp, int n) {
    int bid = blockIdx.x;
    int s = bid & 7;                 // slice (heuristically = XCD via round-robin dispatch)
    int chunk = bid >> 3;
    int tid = threadIdx.x;
    int wave = tid >> 6, lane = tid & 63;
    int slot = lane >> 3;            // neighbor slot 0..7
    int f = lane & 7;                // feature within slice
    const float* S = hs + (size_t)s * NN * SLF;   // 3.2 MB slice region
    float bb = b[s * SLF + f];
    for (int t = 0; t < CHUNK / 4; ++t) {
        int node = chunk * CHUNK + t * 4 + wave;
        if (node >= n) break;
        int rs = rowptr[node], e = rs + cnt[node];
        float acc = 0.f, acc2 = 0.f;
        int i = rs;
        for (; i + 16 <= e; i += 16) {
            int na = __builtin_nontemporal_load(colidx + i + slot);
            int nb = __builtin_nontemporal_load(colidx + i + 8 + slot);
            acc  += S[na * SLF + f];
            acc2 += S[nb * SLF + f];
        }
        if (i + 8 <= e) {
            int na = __builtin_nontemporal_load(colidx + i + slot);
            acc += S[na * SLF + f];
            i += 8;
        }
        if (slot < e - i) {
            int na = __builtin_nontemporal_load(colidx + i + slot);
            acc2 += S[na * SLF + f];
        }
        acc += acc2;
        acc += __shfl_xor(acc, 8, 64);
        acc += __shfl_xor(acc, 16, 64);
        acc += __shfl_xor(acc, 32, 64);
        if (lane < 8) {
            float tot = acc + S[node * SLF + f];       // self loop
            float v = fmaxf(fmaf(tot, dinv[node], bb), 0.f);
            if (POOL) {
                atomicAdd(&outp[((size_t)s * NG + batch[node]) * SLF + f], v);
            } else {
                __builtin_nontemporal_store(v, outp + (size_t)node * FD + s * SLF + f);
            }
        }
    }
}

// out[g][o] = (sum_f pool_s[f/8][g][f%8]/cnt[g] * Wfc[f][o]) + bfc[o]; wave/graph
__global__ void k_final(const float* __restrict__ pool, const int* __restrict__ pcnt,
                        const float* __restrict__ Wfc, const float* __restrict__ bfc,
                        float* __restrict__ out, int ng) {
    int tid = threadIdx.x;
    int wave = tid >> 6, lane = tid & 63;
    int g = blockIdx.x * 4 + wave;
    if (g >= ng) return;
    float inv = 1.0f / fmaxf((float)pcnt[g], 1.0f);
    float s = pool[((size_t)(lane >> 3) * NG + g) * SLF + (lane & 7)] * inv;
    float a0 = s * Wfc[lane * 2 + 0];
    float a1 = s * Wfc[lane * 2 + 1];
#pragma unroll
    for (int off = 32; off > 0; off >>= 1) {
        a0 += __shfl_down(a0, off, 64);
        a1 += __shfl_down(a1, off, 64);
    }
    if (lane == 0) {
        out[g * 2 + 0] = a0 + bfc[0];
        out[g * 2 + 1] = a1 + bfc[1];
    }
}

extern "C" void kernel_launch(void* const* d_in, const int* in_sizes, int n_in,
                              void* d_out, int out_size, void* d_ws, size_t ws_size,
                              hipStream_t stream) {
    const float* x    = (const float*)d_in[0];
    const int*   eidx = (const int*)d_in[1];   // [2][NE]: row0 = src, row1 = dst
    const int*   batch= (const int*)d_in[2];
    const float* W1   = (const float*)d_in[3];
    const float* b1   = (const float*)d_in[4];
    const float* W2   = (const float*)d_in[5];
    const float* b2   = (const float*)d_in[6];
    const float* Wfc  = (const float*)d_in[7];
    const float* bfc  = (const float*)d_in[8];
    float* out = (float*)d_out;

    const int* esrc = eidx;
    const int* edst = eidx + NE;

    char* ws = (char*)d_ws;
    size_t off = 0;
    auto alloc = [&](size_t bytes) {
        char* p = ws + off;
        off += (bytes + 255) & ~(size_t)255;
        return p;
    };
    int*   cnt      = (int*)  alloc(NN * 4);
    int*   rowptr   = (int*)  alloc(NN * 4);
    int*   blockSum = (int*)  alloc(128 * 4);
    int*   blockOff = (int*)  alloc(128 * 4);
    float* dinv     = (float*)alloc(NN * 4);
    int*   colidx   = (int*)  alloc((size_t)NE * 4);
    float* hs       = (float*)alloc((size_t)NN * FD * 4);   // sliced [8][NN][8]
    float* h1       = (float*)alloc((size_t)NN * FD * 4);   // dense row-major
    float* pool     = (float*)alloc((size_t)NSL * NG * SLF * 4);  // sliced [8][NG][8]
    int*   pcnt     = (int*)  alloc(NG * 4);
    // rank aliases h1 (rank last used in k_fill, h1 first written by k_agg_sliced<0>)
    int*   rank     = (int*)h1;
    (void)ws_size;

    hipMemsetAsync(cnt,  0, NN * 4, stream);
    hipMemsetAsync(pool, 0, (size_t)NSL * NG * SLF * 4, stream);
    hipMemsetAsync(pcnt, 0, NG * 4, stream);

    const int GE = (NE + 255) / 256;   // 6250
    const int GN = (NN + 255) / 256;   // 391
    const int GR = (NN + 15) / 16;     // gemm: 16 rows/block
    const int GA = ((NN + CHUNK - 1) / CHUNK) * NSL;   // 782*8 = 6256

    k_count_rank<<<GE, 256, 0, stream>>>(edst, cnt, rank, NE);
    k_scan1<<<SCAN_BLOCKS, 256, 0, stream>>>(cnt, rowptr, blockSum, NN);
    k_scan2<<<1, 128, 0, stream>>>(blockSum, blockOff, SCAN_BLOCKS);
    k_scan3<<<GN, 256, 0, stream>>>(rowptr, blockOff, cnt, dinv, batch, pcnt, NN);
    k_fill<<<GE, 256, 0, stream>>>(esrc, edst, rank, rowptr, colidx, NE);

    // layer 1: hs_sliced = (x @ W1) * dinv ; h1 = relu(dinv * gather(hs) + b1)
    k_gemm_scale<<<GR, 256, 0, stream>>>(x, W1, dinv, hs, NN);
    k_agg_sliced<0><<<GA, 256, 0, stream>>>(hs, rowptr, cnt, colidx, dinv, b1, batch, h1, NN);

    // layer 2: hs_sliced = (h1 @ W2) * dinv ; pool_sliced += relu(...)
    k_gemm_scale<<<GR, 256, 0, stream>>>(h1, W2, dinv, hs, NN);
    k_agg_sliced<1><<<GA, 256, 0, stream>>>(hs, rowptr, cnt, colidx, dinv, b2, batch, pool, NN);

    // readout
    k_final<<<(NG + 3) / 4, 256, 0, stream>>>(pool, pcnt, Wfc, bfc, out, NG);
}

// Round 6
// 490.915 us; speedup vs baseline: 1.7772x; 1.7772x over previous
//
#include <hip/hip_runtime.h>

// TargetModel_78786880077968: 2-layer GCN + mean pool
#define NN 100000      // nodes
#define NE 1600000     // edges
#define NG 512         // graphs
#define FD 64          // feature dim
#define NSL 4          // feature slices (XCD-pinned); 16 bf16 each = 32 B rows
#define CHUNK 128      // nodes per agg block
#define SCAN_CHUNK 1024
#define SCAN_BLOCKS 98  // ceil(NN / SCAN_CHUNK)

// ---- bf16 pack/unpack (RNE; values finite) ----
__device__ inline unsigned pack_bf16x2(float a, float b) {
    unsigned ua = __float_as_uint(a), ub = __float_as_uint(b);
    ua = (ua + 0x7FFFu + ((ua >> 16) & 1u)) >> 16;
    ub = (ub + 0x7FFFu + ((ub >> 16) & 1u)) >> 16;
    return ua | (ub << 16);
}
__device__ inline float bf_lo(unsigned u) { return __uint_as_float(u << 16); }
__device__ inline float bf_hi(unsigned u) { return __uint_as_float(u & 0xFFFF0000u); }

// ---------- CSR build ----------

__global__ void k_count_rank(const int* __restrict__ dst, int* __restrict__ cnt,
                             int* __restrict__ rank, int e) {
    int i = blockIdx.x * 256 + threadIdx.x;
    if (i < e) rank[i] = atomicAdd(&cnt[dst[i]], 1);
}

__global__ void k_scan1(const int* __restrict__ cnt, int* __restrict__ part,
                        int* __restrict__ blockSum, int n) {
    __shared__ int lds[256];
    int tid = threadIdx.x;
    int base = blockIdx.x * SCAN_CHUNK + tid * 4;
    int v0 = (base + 0 < n) ? cnt[base + 0] : 0;
    int v1 = (base + 1 < n) ? cnt[base + 1] : 0;
    int v2 = (base + 2 < n) ? cnt[base + 2] : 0;
    int v3 = (base + 3 < n) ? cnt[base + 3] : 0;
    int s = v0 + v1 + v2 + v3;
    lds[tid] = s;
    __syncthreads();
    for (int off = 1; off < 256; off <<= 1) {
        int t = (tid >= off) ? lds[tid - off] : 0;
        __syncthreads();
        lds[tid] += t;
        __syncthreads();
    }
    int run = lds[tid] - s;
    if (base + 0 < n) part[base + 0] = run; run += v0;
    if (base + 1 < n) part[base + 1] = run; run += v1;
    if (base + 2 < n) part[base + 2] = run; run += v2;
    if (base + 3 < n) part[base + 3] = run;
    if (tid == 255) blockSum[blockIdx.x] = lds[255];
}

__global__ void k_scan2(const int* __restrict__ bs, int* __restrict__ boff, int nb) {
    __shared__ int lds[128];
    int tid = threadIdx.x;
    int v = (tid < nb) ? bs[tid] : 0;
    lds[tid] = v;
    __syncthreads();
    for (int off = 1; off < 128; off <<= 1) {
        int t = (tid >= off) ? lds[tid - off] : 0;
        __syncthreads();
        lds[tid] += t;
        __syncthreads();
    }
    if (tid < nb) boff[tid] = lds[tid] - v;
}

__global__ void k_scan3(int* __restrict__ rowptr, const int* __restrict__ boff,
                        const int* __restrict__ cnt, float* __restrict__ dinv,
                        const int* __restrict__ batch, int* __restrict__ pcnt, int n) {
    int i = blockIdx.x * 256 + threadIdx.x;
    if (i < n) {
        rowptr[i] = rowptr[i] + boff[i >> 10];
        float deg = (float)(cnt[i] + 1);  // +1 self loop
        dinv[i] = 1.0f / sqrtf(deg);
        atomicAdd(&pcnt[batch[i]], 1);
    }
}

__global__ void k_fill(const int* __restrict__ src, const int* __restrict__ dst,
                       const int* __restrict__ rank, const int* __restrict__ rowptr,
                       int* __restrict__ colidx, int e) {
    int i = blockIdx.x * 256 + threadIdx.x;
    if (i < e) {
        int d = dst[i];
        colidx[rowptr[d] + rank[i]] = src[i];
    }
}

// ---------- dense GEMM, sliced bf16 output ----------
// hs[s][row][16 bf16] = bf16( dinv[row] * sum_k in[row][k] * W[k][s*16 + j] )
// 4 waves/block, 4 rows/wave; lane c in 0..15 computes feats 4c..4c+3.
__global__ void k_gemm_scale(const float* __restrict__ in, const float* __restrict__ W,
                             const float* __restrict__ dinv, unsigned* __restrict__ hs, int n) {
    __shared__ float w[FD * FD];        // 16 KB
    __shared__ float xr[4][4][80];      // padded f32 row staging
    int tid = threadIdx.x;
    {
        const float4* W4 = (const float4*)W;
        float4* w4s = (float4*)w;
        for (int i = tid; i < FD * FD / 4; i += 256) w4s[i] = W4[i];
    }
    int wave = tid >> 6, lane = tid & 63;
    int r = lane >> 4;        // row within wave
    int c = lane & 15;        // 4-feature chunk
    int row = blockIdx.x * 16 + wave * 4 + r;
    bool valid = row < n;
    if (valid) {
        float4 xv = ((const float4*)in)[row * 16 + c];
        *((float4*)&xr[wave][r][c * 4]) = xv;
    }
    __syncthreads();
    if (!valid) return;
    const float4* w4 = (const float4*)w;
    float4 acc = {0.f, 0.f, 0.f, 0.f};
#pragma unroll
    for (int k = 0; k < FD; ++k) {
        float xv = xr[wave][r][k];
        float4 wv = w4[k * 16 + c];
        acc.x = fmaf(xv, wv.x, acc.x);
        acc.y = fmaf(xv, wv.y, acc.y);
        acc.z = fmaf(xv, wv.z, acc.z);
        acc.w = fmaf(xv, wv.w, acc.w);
    }
    float d = dinv[row];
    uint2 o;
    o.x = pack_bf16x2(acc.x * d, acc.y * d);
    o.y = pack_bf16x2(acc.z * d, acc.w * d);
    // slice = c>>2; within-slice uint2 index = c&3; row stride = 4 uint2
    ((uint2*)hs)[((size_t)(c >> 2) * NN + row) * 4 + (c & 3)] = o;
}

// ---------- sliced aggregation, software-pipelined ----------
// block -> slice = bid&3 (XCD-affine); wave handles 32 nodes serially.
// lane = (slot 0..7, fp 0..7); slot gathers neighbor rows, fp = bf16-pair.
template <int POOL>
__global__ void k_agg4(const unsigned* __restrict__ hs, const int* __restrict__ rowptr,
                       const int* __restrict__ cnt, const int* __restrict__ colidx,
                       const float* __restrict__ dinv, const float* __restrict__ b,
                       const int* __restrict__ batch, float* __restrict__ outp, int n) {
    int bid = blockIdx.x;
    int s = bid & 3;
    int chunk = bid >> 2;
    int tid = threadIdx.x;
    int wave = tid >> 6, lane = tid & 63;
    int slot = lane >> 3, fp = lane & 7;
    const unsigned* S = hs + (size_t)s * NN * 8;   // 3.2 MB slice (8 dwords/row)
    float b0 = b[s * 16 + fp * 2], b1 = b[s * 16 + fp * 2 + 1];
    int node = chunk * CHUNK + wave;
    if (node >= n) return;
    // prologue: load state for first node
    int rs = rowptr[node], ct = cnt[node];
    float dv = dinv[node];
    int bg = POOL ? batch[node] : 0;
    int c0 = colidx[rs + slot];
    int c1 = colidx[rs + 8 + slot];
    for (int t = 0; t < CHUNK / 4; ++t) {
        // issue current node's gathers (branchless index clamp keeps addr safe)
        bool ok0 = slot < ct, ok1 = slot + 8 < ct;
        int i0 = ok0 ? c0 : node;
        int i1 = ok1 ? c1 : node;
        unsigned w0 = S[(size_t)i0 * 8 + fp];
        unsigned w1 = S[(size_t)i1 * 8 + fp];
        unsigned sv = S[(size_t)node * 8 + fp];   // self row (broadcast line)
        // prefetch next node's state (independent of current gathers)
        int node2 = node + 4;
        int ncl = node2 < n ? node2 : n - 1;
        int rs2 = rowptr[ncl], ct2 = cnt[ncl];
        float dv2 = dinv[ncl];
        int bg2 = POOL ? batch[ncl] : 0;
        int c0n = colidx[rs2 + slot];
        int c1n = colidx[rs2 + 8 + slot];
        // accumulate (masked)
        w0 = ok0 ? w0 : 0u;
        w1 = ok1 ? w1 : 0u;
        float a0 = bf_lo(w0) + bf_lo(w1);
        float a1 = bf_hi(w0) + bf_hi(w1);
        // tail for degree > 16
        int e = rs + ct;
        for (int i = rs + 16; i < e; i += 8) {
            int cc = colidx[i + slot];     // colidx padded; garbage masked below
            bool ok = (i + slot) < e;
            int ii = ok ? cc : node;
            unsigned ww = S[(size_t)ii * 8 + fp];
            ww = ok ? ww : 0u;
            a0 += bf_lo(ww);
            a1 += bf_hi(ww);
        }
        // reduce across 8 slots
        a0 += __shfl_xor(a0, 8, 64);  a1 += __shfl_xor(a1, 8, 64);
        a0 += __shfl_xor(a0, 16, 64); a1 += __shfl_xor(a1, 16, 64);
        a0 += __shfl_xor(a0, 32, 64); a1 += __shfl_xor(a1, 32, 64);
        if (lane < 8) {
            float t0 = a0 + bf_lo(sv), t1 = a1 + bf_hi(sv);
            float r0 = fmaxf(fmaf(t0, dv, b0), 0.f);
            float r1 = fmaxf(fmaf(t1, dv, b1), 0.f);
            if (POOL) {
                float* p = &outp[((size_t)s * NG + bg) * 16 + fp * 2];
                atomicAdd(p + 0, r0);
                atomicAdd(p + 1, r1);
            } else {
                float2 o = {r0, r1};
                *(float2*)(outp + (size_t)node * FD + s * 16 + fp * 2) = o;
            }
        }
        // rotate state
        node = node2;
        if (node >= n) break;      // uniform within wave
        rs = rs2; ct = ct2; dv = dv2; bg = bg2; c0 = c0n; c1 = c1n;
    }
}

// out[g][o] = (sum_f pool_s[f/16][g][f%16]/cnt[g] * Wfc[f][o]) + bfc[o]; wave/graph
__global__ void k_final(const float* __restrict__ pool, const int* __restrict__ pcnt,
                        const float* __restrict__ Wfc, const float* __restrict__ bfc,
                        float* __restrict__ out, int ng) {
    int tid = threadIdx.x;
    int wave = tid >> 6, lane = tid & 63;
    int g = blockIdx.x * 4 + wave;
    if (g >= ng) return;
    float inv = 1.0f / fmaxf((float)pcnt[g], 1.0f);
    float s = pool[((size_t)(lane >> 4) * NG + g) * 16 + (lane & 15)] * inv;
    float a0 = s * Wfc[lane * 2 + 0];
    float a1 = s * Wfc[lane * 2 + 1];
#pragma unroll
    for (int off = 32; off > 0; off >>= 1) {
        a0 += __shfl_down(a0, off, 64);
        a1 += __shfl_down(a1, off, 64);
    }
    if (lane == 0) {
        out[g * 2 + 0] = a0 + bfc[0];
        out[g * 2 + 1] = a1 + bfc[1];
    }
}

extern "C" void kernel_launch(void* const* d_in, const int* in_sizes, int n_in,
                              void* d_out, int out_size, void* d_ws, size_t ws_size,
                              hipStream_t stream) {
    const float* x    = (const float*)d_in[0];
    const int*   eidx = (const int*)d_in[1];   // [2][NE]: row0 = src, row1 = dst
    const int*   batch= (const int*)d_in[2];
    const float* W1   = (const float*)d_in[3];
    const float* b1   = (const float*)d_in[4];
    const float* W2   = (const float*)d_in[5];
    const float* b2   = (const float*)d_in[6];
    const float* Wfc  = (const float*)d_in[7];
    const float* bfc  = (const float*)d_in[8];
    float* out = (float*)d_out;

    const int* esrc = eidx;
    const int* edst = eidx + NE;

    char* ws = (char*)d_ws;
    size_t off = 0;
    auto alloc = [&](size_t bytes) {
        char* p = ws + off;
        off += (bytes + 255) & ~(size_t)255;
        return p;
    };
    int*      cnt      = (int*)     alloc(NN * 4);
    int*      rowptr   = (int*)     alloc(NN * 4);
    int*      blockSum = (int*)     alloc(128 * 4);
    int*      blockOff = (int*)     alloc(128 * 4);
    float*    dinv     = (float*)   alloc(NN * 4);
    int*      colidx   = (int*)     alloc((size_t)(NE + 64) * 4);  // +pad for slot overreach
    unsigned* hs       = (unsigned*)alloc((size_t)NN * FD * 2);    // bf16 sliced [4][NN][16]
    float*    h1       = (float*)   alloc((size_t)NN * FD * 4);    // f32 dense
    float*    pool     = (float*)   alloc((size_t)NSL * NG * 16 * 4);  // sliced [4][NG][16]
    int*      pcnt     = (int*)     alloc(NG * 4);
    // rank aliases h1 (rank last used in k_fill, h1 first written by k_agg4<0>)
    int*      rank     = (int*)h1;
    (void)ws_size;

    hipMemsetAsync(cnt,  0, NN * 4, stream);
    hipMemsetAsync(pool, 0, (size_t)NSL * NG * 16 * 4, stream);
    hipMemsetAsync(pcnt, 0, NG * 4, stream);

    const int GE = (NE + 255) / 256;   // 6250
    const int GN = (NN + 255) / 256;   // 391
    const int GR = (NN + 15) / 16;     // gemm: 16 rows/block
    const int GA = ((NN + CHUNK - 1) / CHUNK) * NSL;   // 782*4 = 3128

    k_count_rank<<<GE, 256, 0, stream>>>(edst, cnt, rank, NE);
    k_scan1<<<SCAN_BLOCKS, 256, 0, stream>>>(cnt, rowptr, blockSum, NN);
    k_scan2<<<1, 128, 0, stream>>>(blockSum, blockOff, SCAN_BLOCKS);
    k_scan3<<<GN, 256, 0, stream>>>(rowptr, blockOff, cnt, dinv, batch, pcnt, NN);
    k_fill<<<GE, 256, 0, stream>>>(esrc, edst, rank, rowptr, colidx, NE);

    // layer 1: hs = bf16_sliced((x @ W1) * dinv); h1 = relu(dinv * gather(hs) + b1)
    k_gemm_scale<<<GR, 256, 0, stream>>>(x, W1, dinv, hs, NN);
    k_agg4<0><<<GA, 256, 0, stream>>>(hs, rowptr, cnt, colidx, dinv, b1, batch, h1, NN);

    // layer 2: hs = bf16_sliced((h1 @ W2) * dinv); pool += relu(...)
    k_gemm_scale<<<GR, 256, 0, stream>>>(h1, W2, dinv, hs, NN);
    k_agg4<1><<<GA, 256, 0, stream>>>(hs, rowptr, cnt, colidx, dinv, b2, batch, pool, NN);

    // readout
    k_final<<<(NG + 3) / 4, 256, 0, stream>>>(pool, pcnt, Wfc, bfc, out, NG);
}

// Round 7
// 404.688 us; speedup vs baseline: 2.1559x; 1.2131x over previous
//
#include <hip/hip_runtime.h>

// TargetModel_78786880077968: 2-layer GCN + mean pool
#define NN 100000      // nodes
#define NE 1600000     // edges
#define NG 512         // graphs
#define FD 64          // feature dim
#define NSL 4          // feature slices (XCD-pinned); 16 bf16 each = 32 B rows
#define CHUNK 128      // nodes per agg block
#define SCAN_CHUNK 1024
#define SCAN_BLOCKS 98  // ceil(NN / SCAN_CHUNK)

// ---- bf16 pack/unpack (RNE; values finite) ----
__device__ inline unsigned pack_bf16x2(float a, float b) {
    unsigned ua = __float_as_uint(a), ub = __float_as_uint(b);
    ua = (ua + 0x7FFFu + ((ua >> 16) & 1u)) >> 16;
    ub = (ub + 0x7FFFu + ((ub >> 16) & 1u)) >> 16;
    return ua | (ub << 16);
}
__device__ inline float bf_lo(unsigned u) { return __uint_as_float(u << 16); }
__device__ inline float bf_hi(unsigned u) { return __uint_as_float(u & 0xFFFF0000u); }

// ---------- CSR build ----------

__global__ void k_count_rank(const int* __restrict__ dst, int* __restrict__ cnt,
                             int* __restrict__ rank, int e) {
    int i = blockIdx.x * 256 + threadIdx.x;
    if (i < e) rank[i] = atomicAdd(&cnt[dst[i]], 1);
}

__global__ void k_scan1(const int* __restrict__ cnt, int* __restrict__ part,
                        int* __restrict__ blockSum, int n) {
    __shared__ int lds[256];
    int tid = threadIdx.x;
    int base = blockIdx.x * SCAN_CHUNK + tid * 4;
    int v0 = (base + 0 < n) ? cnt[base + 0] : 0;
    int v1 = (base + 1 < n) ? cnt[base + 1] : 0;
    int v2 = (base + 2 < n) ? cnt[base + 2] : 0;
    int v3 = (base + 3 < n) ? cnt[base + 3] : 0;
    int s = v0 + v1 + v2 + v3;
    lds[tid] = s;
    __syncthreads();
    for (int off = 1; off < 256; off <<= 1) {
        int t = (tid >= off) ? lds[tid - off] : 0;
        __syncthreads();
        lds[tid] += t;
        __syncthreads();
    }
    int run = lds[tid] - s;
    if (base + 0 < n) part[base + 0] = run; run += v0;
    if (base + 1 < n) part[base + 1] = run; run += v1;
    if (base + 2 < n) part[base + 2] = run; run += v2;
    if (base + 3 < n) part[base + 3] = run;
    if (tid == 255) blockSum[blockIdx.x] = lds[255];
}

__global__ void k_scan2(const int* __restrict__ bs, int* __restrict__ boff, int nb) {
    __shared__ int lds[128];
    int tid = threadIdx.x;
    int v = (tid < nb) ? bs[tid] : 0;
    lds[tid] = v;
    __syncthreads();
    for (int off = 1; off < 128; off <<= 1) {
        int t = (tid >= off) ? lds[tid - off] : 0;
        __syncthreads();
        lds[tid] += t;
        __syncthreads();
    }
    if (tid < nb) boff[tid] = lds[tid] - v;
}

// finalize rowptr + dinv (no atomics)
__global__ void k_scan3(int* __restrict__ rowptr, const int* __restrict__ boff,
                        const int* __restrict__ cnt, float* __restrict__ dinv, int n) {
    int i = blockIdx.x * 256 + threadIdx.x;
    if (i < n) {
        rowptr[i] = rowptr[i] + boff[i >> 10];
        float deg = (float)(cnt[i] + 1);  // +1 self loop
        dinv[i] = 1.0f / sqrtf(deg);
    }
}

// per-graph node counts via binary search over sorted batch (no atomics)
__global__ void k_pcnt_bs(const int* __restrict__ batch, int* __restrict__ pcnt, int n, int ng) {
    int g = blockIdx.x * 256 + threadIdx.x;
    if (g >= ng) return;
    int lo = 0, hi = n;
    while (lo < hi) { int m = (lo + hi) >> 1; if (batch[m] < g) lo = m + 1; else hi = m; }
    int l0 = lo;
    lo = 0; hi = n;
    int v = g + 1;
    while (lo < hi) { int m = (lo + hi) >> 1; if (batch[m] < v) lo = m + 1; else hi = m; }
    pcnt[g] = lo - l0;
}

__global__ void k_fill(const int* __restrict__ src, const int* __restrict__ dst,
                       const int* __restrict__ rank, const int* __restrict__ rowptr,
                       int* __restrict__ colidx, int e) {
    int i = blockIdx.x * 256 + threadIdx.x;
    if (i < e) {
        int d = dst[i];
        colidx[rowptr[d] + rank[i]] = src[i];
    }
}

// ---------- dense GEMM, sliced bf16 output ----------
// hs[s][row][16 bf16] = bf16( dinv[row] * sum_k in[row][k] * W[k][s*16 + j] )
__global__ void k_gemm_scale(const float* __restrict__ in, const float* __restrict__ W,
                             const float* __restrict__ dinv, unsigned* __restrict__ hs, int n) {
    __shared__ float w[FD * FD];        // 16 KB
    __shared__ float xr[4][4][80];      // padded f32 row staging
    int tid = threadIdx.x;
    {
        const float4* W4 = (const float4*)W;
        float4* w4s = (float4*)w;
        for (int i = tid; i < FD * FD / 4; i += 256) w4s[i] = W4[i];
    }
    int wave = tid >> 6, lane = tid & 63;
    int r = lane >> 4;        // row within wave
    int c = lane & 15;        // 4-feature chunk
    int row = blockIdx.x * 16 + wave * 4 + r;
    bool valid = row < n;
    if (valid) {
        float4 xv = ((const float4*)in)[row * 16 + c];
        *((float4*)&xr[wave][r][c * 4]) = xv;
    }
    __syncthreads();
    if (!valid) return;
    const float4* w4 = (const float4*)w;
    float4 acc = {0.f, 0.f, 0.f, 0.f};
#pragma unroll
    for (int k = 0; k < FD; ++k) {
        float xv = xr[wave][r][k];
        float4 wv = w4[k * 16 + c];
        acc.x = fmaf(xv, wv.x, acc.x);
        acc.y = fmaf(xv, wv.y, acc.y);
        acc.z = fmaf(xv, wv.z, acc.z);
        acc.w = fmaf(xv, wv.w, acc.w);
    }
    float d = dinv[row];
    uint2 o;
    o.x = pack_bf16x2(acc.x * d, acc.y * d);
    o.y = pack_bf16x2(acc.z * d, acc.w * d);
    // slice = c>>2; within-slice uint2 index = c&3; row stride = 4 uint2
    ((uint2*)hs)[((size_t)(c >> 2) * NN + row) * 4 + (c & 3)] = o;
}

// ---------- sliced aggregation, software-pipelined ----------
// block -> slice = bid&3 (XCD-affine); wave handles 32 nodes serially.
// lane = (slot 0..7, fp 0..7); slot gathers neighbor rows, fp = bf16-pair.
template <int POOL>
__global__ void k_agg4(const unsigned* __restrict__ hs, const int* __restrict__ rowptr,
                       const int* __restrict__ cnt, const int* __restrict__ colidx,
                       const float* __restrict__ dinv, const float* __restrict__ b,
                       const int* __restrict__ batch, float* __restrict__ outp, int n) {
    int bid = blockIdx.x;
    int s = bid & 3;
    int chunk = bid >> 2;
    int tid = threadIdx.x;
    int wave = tid >> 6, lane = tid & 63;
    int slot = lane >> 3, fp = lane & 7;
    const unsigned* S = hs + (size_t)s * NN * 8;   // 3.2 MB slice (8 dwords/row)
    float b0 = b[s * 16 + fp * 2], b1 = b[s * 16 + fp * 2 + 1];
    int node = chunk * CHUNK + wave;
    if (node >= n) return;
    // prologue: load state for first node
    int rs = rowptr[node], ct = cnt[node];
    float dv = dinv[node];
    int bg = POOL ? batch[node] : 0;
    int c0 = colidx[rs + slot];
    int c1 = colidx[rs + 8 + slot];
    for (int t = 0; t < CHUNK / 4; ++t) {
        // issue current node's gathers (branchless index clamp keeps addr safe)
        bool ok0 = slot < ct, ok1 = slot + 8 < ct;
        int i0 = ok0 ? c0 : node;
        int i1 = ok1 ? c1 : node;
        unsigned w0 = S[(size_t)i0 * 8 + fp];
        unsigned w1 = S[(size_t)i1 * 8 + fp];
        unsigned sv = S[(size_t)node * 8 + fp];   // self row (broadcast line)
        // prefetch next node's state (independent of current gathers)
        int node2 = node + 4;
        int ncl = node2 < n ? node2 : n - 1;
        int rs2 = rowptr[ncl], ct2 = cnt[ncl];
        float dv2 = dinv[ncl];
        int bg2 = POOL ? batch[ncl] : 0;
        int c0n = colidx[rs2 + slot];
        int c1n = colidx[rs2 + 8 + slot];
        // accumulate (masked)
        w0 = ok0 ? w0 : 0u;
        w1 = ok1 ? w1 : 0u;
        float a0 = bf_lo(w0) + bf_lo(w1);
        float a1 = bf_hi(w0) + bf_hi(w1);
        // tail for degree > 16
        int e = rs + ct;
        for (int i = rs + 16; i < e; i += 8) {
            int cc = colidx[i + slot];     // colidx padded; garbage masked below
            bool ok = (i + slot) < e;
            int ii = ok ? cc : node;
            unsigned ww = S[(size_t)ii * 8 + fp];
            ww = ok ? ww : 0u;
            a0 += bf_lo(ww);
            a1 += bf_hi(ww);
        }
        // reduce across 8 slots
        a0 += __shfl_xor(a0, 8, 64);  a1 += __shfl_xor(a1, 8, 64);
        a0 += __shfl_xor(a0, 16, 64); a1 += __shfl_xor(a1, 16, 64);
        a0 += __shfl_xor(a0, 32, 64); a1 += __shfl_xor(a1, 32, 64);
        if (lane < 8) {
            float t0 = a0 + bf_lo(sv), t1 = a1 + bf_hi(sv);
            float r0 = fmaxf(fmaf(t0, dv, b0), 0.f);
            float r1 = fmaxf(fmaf(t1, dv, b1), 0.f);
            if (POOL) {
                float* p = &outp[((size_t)s * NG + bg) * 16 + fp * 2];
                atomicAdd(p + 0, r0);
                atomicAdd(p + 1, r1);
            } else {
                float2 o = {r0, r1};
                *(float2*)(outp + (size_t)node * FD + s * 16 + fp * 2) = o;
            }
        }
        // rotate state
        node = node2;
        if (node >= n) break;      // uniform within wave
        rs = rs2; ct = ct2; dv = dv2; bg = bg2; c0 = c0n; c1 = c1n;
    }
}

// out[g][o] = (sum_f pool_s[f/16][g][f%16]/cnt[g] * Wfc[f][o]) + bfc[o]; wave/graph
__global__ void k_final(const float* __restrict__ pool, const int* __restrict__ pcnt,
                        const float* __restrict__ Wfc, const float* __restrict__ bfc,
                        float* __restrict__ out, int ng) {
    int tid = threadIdx.x;
    int wave = tid >> 6, lane = tid & 63;
    int g = blockIdx.x * 4 + wave;
    if (g >= ng) return;
    float inv = 1.0f / fmaxf((float)pcnt[g], 1.0f);
    float s = pool[((size_t)(lane >> 4) * NG + g) * 16 + (lane & 15)] * inv;
    float a0 = s * Wfc[lane * 2 + 0];
    float a1 = s * Wfc[lane * 2 + 1];
#pragma unroll
    for (int off = 32; off > 0; off >>= 1) {
        a0 += __shfl_down(a0, off, 64);
        a1 += __shfl_down(a1, off, 64);
    }
    if (lane == 0) {
        out[g * 2 + 0] = a0 + bfc[0];
        out[g * 2 + 1] = a1 + bfc[1];
    }
}

extern "C" void kernel_launch(void* const* d_in, const int* in_sizes, int n_in,
                              void* d_out, int out_size, void* d_ws, size_t ws_size,
                              hipStream_t stream) {
    const float* x    = (const float*)d_in[0];
    const int*   eidx = (const int*)d_in[1];   // [2][NE]: row0 = src, row1 = dst
    const int*   batch= (const int*)d_in[2];
    const float* W1   = (const float*)d_in[3];
    const float* b1   = (const float*)d_in[4];
    const float* W2   = (const float*)d_in[5];
    const float* b2   = (const float*)d_in[6];
    const float* Wfc  = (const float*)d_in[7];
    const float* bfc  = (const float*)d_in[8];
    float* out = (float*)d_out;

    const int* esrc = eidx;
    const int* edst = eidx + NE;

    char* ws = (char*)d_ws;
    size_t off = 0;
    auto alloc = [&](size_t bytes) {
        char* p = ws + off;
        off += (bytes + 255) & ~(size_t)255;
        return p;
    };
    int*      cnt      = (int*)     alloc(NN * 4);
    int*      rowptr   = (int*)     alloc(NN * 4);
    int*      blockSum = (int*)     alloc(128 * 4);
    int*      blockOff = (int*)     alloc(128 * 4);
    float*    dinv     = (float*)   alloc(NN * 4);
    int*      colidx   = (int*)     alloc((size_t)(NE + 64) * 4);  // +pad for slot overreach
    unsigned* hs       = (unsigned*)alloc((size_t)NN * FD * 2);    // bf16 sliced [4][NN][16]
    float*    h1       = (float*)   alloc((size_t)NN * FD * 4);    // f32 dense
    float*    pool     = (float*)   alloc((size_t)NSL * NG * 16 * 4);  // sliced [4][NG][16]
    int*      pcnt     = (int*)     alloc(NG * 4);
    // rank aliases h1 (rank last used in k_fill, h1 first written by k_agg4<0>)
    int*      rank     = (int*)h1;
    (void)ws_size;

    hipMemsetAsync(cnt,  0, NN * 4, stream);
    hipMemsetAsync(pool, 0, (size_t)NSL * NG * 16 * 4, stream);

    const int GE = (NE + 255) / 256;   // 6250
    const int GN = (NN + 255) / 256;   // 391
    const int GR = (NN + 15) / 16;     // gemm: 16 rows/block
    const int GA = ((NN + CHUNK - 1) / CHUNK) * NSL;   // 782*4 = 3128

    k_count_rank<<<GE, 256, 0, stream>>>(edst, cnt, rank, NE);
    k_scan1<<<SCAN_BLOCKS, 256, 0, stream>>>(cnt, rowptr, blockSum, NN);
    k_scan2<<<1, 128, 0, stream>>>(blockSum, blockOff, SCAN_BLOCKS);
    k_scan3<<<GN, 256, 0, stream>>>(rowptr, blockOff, cnt, dinv, NN);
    k_pcnt_bs<<<2, 256, 0, stream>>>(batch, pcnt, NN, NG);
    k_fill<<<GE, 256, 0, stream>>>(esrc, edst, rank, rowptr, colidx, NE);

    // layer 1: hs = bf16_sliced((x @ W1) * dinv); h1 = relu(dinv * gather(hs) + b1)
    k_gemm_scale<<<GR, 256, 0, stream>>>(x, W1, dinv, hs, NN);
    k_agg4<0><<<GA, 256, 0, stream>>>(hs, rowptr, cnt, colidx, dinv, b1, batch, h1, NN);

    // layer 2: hs = bf16_sliced((h1 @ W2) * dinv); pool += relu(...)
    k_gemm_scale<<<GR, 256, 0, stream>>>(h1, W2, dinv, hs, NN);
    k_agg4<1><<<GA, 256, 0, stream>>>(hs, rowptr, cnt, colidx, dinv, b2, batch, pool, NN);

    // readout
    k_final<<<(NG + 3) / 4, 256, 0, stream>>>(pool, pcnt, Wfc, bfc, out, NG);
}